// Round 12
// baseline (52.764 us; speedup 1.0000x reference)
//
#include <hip/hip_runtime.h>
#include <hip/hip_bf16.h>

#define IN_F  4096
#define OUT_F 11008
#define WSTR  68            // halfs per LDS row (136 B stride)
#define WV_W  (16 * WSTR * 2)          // 2176 B: W tile
#define WV_X  (32 * WSTR * 2)          // 4352 B: X tile (red aliases this)
#define WV_BYTES (WV_W + WV_X)         // 6528 B per wave; x8 = 51.0 KB

typedef _Float16 half8 __attribute__((ext_vector_type(8)));
typedef _Float16 half4 __attribute__((ext_vector_type(4)));
typedef __fp16   fp16x2 __attribute__((ext_vector_type(2)));
typedef float    f32x4 __attribute__((ext_vector_type(4)));
typedef int      i32x4 __attribute__((ext_vector_type(4)));

// Single fused kernel. Block: 16 output channels, 512 threads = 8 waves.
// Wave w owns K slice [w*512, w*512+512) = 8 chunks of 64 k.
//  - W: COALESCED -> regs (2-deep chunk ring) -> cvt_pkrtz fp16 ->
//       wave-private LDS [16][68] -> ds_read_b128 fragments.
//  - X: COALESCED (8 rows x dense 128B) -> regs (single-buffered; L2-resident,
//       TLP at 6 waves/SIMD covers ~300cy) -> cvt_pkrtz -> LDS [32][68].
//  - reduction buffer ALIASES the X tile (used only after last xlds read;
//    per-wave LDS ops are in-order; cross-wave reads gated by __syncthreads).
//  - LDS 51.0 KB + VGPR<=85 => 3 blocks/CU => all 688 blocks co-resident,
//    no dispatch tail.
__global__ __launch_bounds__(512, 6)
void dql_fused(const float* __restrict__ x,      // [32][4096] f32 (exact fp16 vals)
               const int* __restrict__ wq,       // [11008][4096] int32 in [-127,127]
               const float* __restrict__ scale,  // [11008]
               const float* __restrict__ bias,   // [11008]
               float* __restrict__ out)          // [32][11008]
{
    __shared__ __align__(16) unsigned char smem[8][WV_BYTES];

    const int tid  = threadIdx.x;
    const int wid  = tid >> 6;
    const int lane = tid & 63;
    const int c    = lane & 15;           // fragment: channel row / token row
    const int kg   = lane >> 4;           // fragment: k-group (8 k each)
    const int srow = lane >> 2;           // W staging: row (0..15)
    const int scol = (lane & 3) * 4;      // W staging: half offset in chunk
    const int xr   = lane >> 3;           // X staging: row-in-group (0..7)
    const int xc   = (lane & 7) * 4;      // X staging: col offset (f32s/halfs)
    const int obase = blockIdx.x * 16;
    const int kbase = wid * 512;

    _Float16* wlds = (_Float16*)(&smem[wid][0]);      // [16][WSTR]
    _Float16* xlds = (_Float16*)(&smem[wid][WV_W]);   // [32][WSTR]

    const int* wrow = wq + (size_t)(obase + srow) * IN_F + kbase + scol;
    const float* xb0 = x + (size_t)xr * IN_F + kbase + xc;

    f32x4 acc0 = {0.f, 0.f, 0.f, 0.f};
    f32x4 acc1 = {0.f, 0.f, 0.f, 0.f};

    i32x4 w0[4], w1[4];   // 2-deep W chunk ring
    f32x4 xh[4];          // single-buffered X half-chunk

    auto LOADW = [&](i32x4* wbuf, int ch) {
        #pragma unroll
        for (int i = 0; i < 4; ++i)
            wbuf[i] = *(const i32x4*)(wrow + ch * 64 + i * 16);
    };
    auto LOADXH = [&](int ch, int sub) {
        #pragma unroll
        for (int q2 = 0; q2 < 4; ++q2)
            xh[q2] = *(const f32x4*)(xb0 + (size_t)q2 * 8 * IN_F + ch * 64 + sub * 32);
    };
    auto STAGEW = [&](i32x4* wbuf) {
        #pragma unroll
        for (int i = 0; i < 4; ++i) {
            union { fp16x2 v2[2]; half4 v4; } u;
            u.v2[0] = __builtin_amdgcn_cvt_pkrtz((float)wbuf[i][0], (float)wbuf[i][1]);
            u.v2[1] = __builtin_amdgcn_cvt_pkrtz((float)wbuf[i][2], (float)wbuf[i][3]);
            *(half4*)&wlds[srow * WSTR + scol + i * 16] = u.v4;
        }
    };
    auto STAGEXH = [&](int sub) {
        #pragma unroll
        for (int q2 = 0; q2 < 4; ++q2) {
            union { fp16x2 v2[2]; half4 v4; } u;
            u.v2[0] = __builtin_amdgcn_cvt_pkrtz(xh[q2][0], xh[q2][1]);
            u.v2[1] = __builtin_amdgcn_cvt_pkrtz(xh[q2][2], xh[q2][3]);
            *(half4*)&xlds[(q2 * 8 + xr) * WSTR + sub * 32 + xc] = u.v4;
        }
    };
    auto COMPUTE = [&](int sub) {
        half8 wf  = *(half8*)&wlds[c * WSTR + sub * 32 + kg * 8];
        half8 xf0 = *(half8*)&xlds[c * WSTR + sub * 32 + kg * 8];
        half8 xf1 = *(half8*)&xlds[(16 + c) * WSTR + sub * 32 + kg * 8];
        acc0 = __builtin_amdgcn_mfma_f32_16x16x32_f16(xf0, wf, acc0, 0, 0, 0);
        acc1 = __builtin_amdgcn_mfma_f32_16x16x32_f16(xf1, wf, acc1, 0, 0, 0);
    };

    LOADW(w0, 0); LOADW(w1, 1);

    #pragma unroll
    for (int ch = 0; ch < 8; ++ch) {
        i32x4* wcur = (ch & 1) ? w1 : w0;
        STAGEW(wcur);
        LOADXH(ch, 0); STAGEXH(0); COMPUTE(0);
        LOADXH(ch, 1); STAGEXH(1); COMPUTE(1);
        if (ch + 2 < 8) LOADW(wcur, ch + 2);
    }

    // write partials into this wave's red region (aliases xlds; safe:
    // all of this wave's xlds reads precede these writes in program order
    // and per-wave LDS ops execute in order)
    float* redw = (float*)(&smem[wid][WV_W]);   // [64][9]
    #pragma unroll
    for (int r = 0; r < 4; ++r) {
        redw[lane * 9 + r]     = acc0[r];
        redw[lane * 9 + 4 + r] = acc1[r];
    }
    __syncthreads();

    // 512 threads: one (lane, slot) each; sum the 8 wave partials.
    const int rlane = tid & 63;
    const int slot  = tid >> 6;          // 0..7 : (token-half h = slot>>2, reg r = slot&3)
    float s = 0.f;
    #pragma unroll
    for (int wv = 0; wv < 8; ++wv)
        s += ((const float*)(&smem[wv][WV_W]))[rlane * 9 + slot];

    const int h = slot >> 2;
    const int r = slot & 3;
    const int t = h * 16 + (rlane >> 4) * 4 + r;   // token
    const int o = obase + (rlane & 15);            // output channel

    out[t * OUT_F + o] = s * scale[o] + bias[o];
}

extern "C" void kernel_launch(void* const* d_in, const int* in_sizes, int n_in,
                              void* d_out, int out_size, void* d_ws, size_t ws_size,
                              hipStream_t stream) {
    const float* x     = (const float*)d_in[0];
    const int*   wq    = (const int*)d_in[1];
    const float* scale = (const float*)d_in[2];
    const float* bias  = (const float*)d_in[3];
    float*       out   = (float*)d_out;

    dql_fused<<<OUT_F / 16, 512, 0, stream>>>(x, wq, scale, bias, out);
}

// Round 13
// 34.750 us; speedup vs baseline: 1.5184x; 1.5184x over previous
//
#include <hip/hip_runtime.h>
#include <hip/hip_bf16.h>

#define IN_F  4096
#define OUT_F 11008

typedef _Float16 half8 __attribute__((ext_vector_type(8)));
typedef _Float16 half4 __attribute__((ext_vector_type(4)));
typedef __fp16   fp16x2 __attribute__((ext_vector_type(2)));
typedef float    f32x4 __attribute__((ext_vector_type(4)));
typedef int      i32x4 __attribute__((ext_vector_type(4)));

// Single fused kernel (best verified: 34.59 us). Block: 16 output channels,
// 512 threads = 8 waves. Wave w owns K slice [w*512, w*512+512) = 8 chunks
// of 64 k.
//  - W: COALESCED (16 rows x dense 256B/chunk) -> regs (2-deep ring) ->
//       cvt_pkrtz fp16 -> wave-private LDS [16][72] -> ds_read_b128 frags.
//  - X: COALESCED (8 rows x dense 128B segments per load-group) -> regs
//       (half-chunk 2-deep) -> cvt_pkrtz fp16 -> wave-private LDS [32][72]
//       -> ds_read_b128 frags. x is L2-resident (512 KB), short latency.
//  - no main-loop __syncthreads, no workspace, one dispatch.
// 2 blocks/CU (73.7 KB LDS). 3 blocks/CU requires <=85 VGPR -> spills (R12);
// this occupancy is the feasible optimum for the dataflow.
__global__ __launch_bounds__(512, 4)
void dql_fused(const float* __restrict__ x,      // [32][4096] f32 (exact fp16 vals)
               const int* __restrict__ wq,       // [11008][4096] int32 in [-127,127]
               const float* __restrict__ scale,  // [11008]
               const float* __restrict__ bias,   // [11008]
               float* __restrict__ out)          // [32][11008]
{
    __shared__ __align__(16) _Float16 wlds[8][16][72];  // 144B row stride
    __shared__ __align__(16) _Float16 xlds[8][32][72];  // 144B row stride
    __shared__ float red[8][64][9];

    const int tid  = threadIdx.x;
    const int wid  = tid >> 6;
    const int lane = tid & 63;
    const int c    = lane & 15;           // fragment: channel row / token row
    const int kg   = lane >> 4;           // fragment: k-group (8 k each)
    const int srow = lane >> 2;           // W staging: row (0..15)
    const int scol = (lane & 3) * 4;      // W staging: int offset in chunk
    const int xr   = lane >> 3;           // X staging: row-in-group (0..7)
    const int xc   = (lane & 7) * 4;      // X staging: f32 col offset
    const int obase = blockIdx.x * 16;
    const int kbase = wid * 512;

    const int* wrow = wq + (size_t)(obase + srow) * IN_F + kbase + scol;
    // X load base for row-group q2 (rows q2*8 + xr), col kbase + ch*64 + sub*32 + xc
    const float* xb0 = x + (size_t)xr * IN_F + kbase + xc;

    f32x4 acc0 = {0.f, 0.f, 0.f, 0.f};
    f32x4 acc1 = {0.f, 0.f, 0.f, 0.f};

    i32x4 w0[4], w1[4];       // 2-deep W chunk ring
    f32x4 xh0[4], xh1[4];     // 2-deep X half-chunk (sub) buffers

    auto LOADW = [&](i32x4* wbuf, int ch) {
        #pragma unroll
        for (int i = 0; i < 4; ++i)
            wbuf[i] = *(const i32x4*)(wrow + ch * 64 + i * 16);
    };
    auto LOADXH = [&](f32x4* xbuf, int ch, int sub) {
        #pragma unroll
        for (int q2 = 0; q2 < 4; ++q2)
            xbuf[q2] = *(const f32x4*)(xb0 + (size_t)q2 * 8 * IN_F + ch * 64 + sub * 32);
    };
    auto STAGEW = [&](i32x4* wbuf) {
        #pragma unroll
        for (int i = 0; i < 4; ++i) {
            union { fp16x2 v2[2]; half4 v4; } u;
            u.v2[0] = __builtin_amdgcn_cvt_pkrtz((float)wbuf[i][0], (float)wbuf[i][1]);
            u.v2[1] = __builtin_amdgcn_cvt_pkrtz((float)wbuf[i][2], (float)wbuf[i][3]);
            *(half4*)&wlds[wid][srow][scol + i * 16] = u.v4;
        }
    };
    auto STAGEXH = [&](f32x4* xbuf, int sub) {
        #pragma unroll
        for (int q2 = 0; q2 < 4; ++q2) {
            union { fp16x2 v2[2]; half4 v4; } u;
            u.v2[0] = __builtin_amdgcn_cvt_pkrtz(xbuf[q2][0], xbuf[q2][1]);
            u.v2[1] = __builtin_amdgcn_cvt_pkrtz(xbuf[q2][2], xbuf[q2][3]);
            *(half4*)&xlds[wid][q2 * 8 + xr][sub * 32 + xc] = u.v4;
        }
    };
    auto COMPUTE = [&](int sub) {
        half8 wf  = *(half8*)&wlds[wid][c][sub * 32 + kg * 8];
        half8 xf0 = *(half8*)&xlds[wid][c][sub * 32 + kg * 8];
        half8 xf1 = *(half8*)&xlds[wid][16 + c][sub * 32 + kg * 8];
        acc0 = __builtin_amdgcn_mfma_f32_16x16x32_f16(xf0, wf, acc0, 0, 0, 0);
        acc1 = __builtin_amdgcn_mfma_f32_16x16x32_f16(xf1, wf, acc1, 0, 0, 0);
    };

    // prologue: 2 W chunks + first X half in flight
    LOADW(w0, 0); LOADW(w1, 1);
    LOADXH(xh0, 0, 0);

    #pragma unroll
    for (int ch = 0; ch < 8; ++ch) {
        i32x4* wcur = (ch & 1) ? w1 : w0;
        STAGEW(wcur);                       // wlds <- chunk ch
        // sub 0
        LOADXH(xh1, ch, 1);                 // prefetch next half
        STAGEXH(xh0, 0);
        COMPUTE(0);
        // sub 1
        if (ch + 1 < 8) LOADXH(xh0, ch + 1, 0);
        STAGEXH(xh1, 1);
        COMPUTE(1);
        // refill consumed W buffer with chunk ch+2
        if (ch + 2 < 8) LOADW(wcur, ch + 2);
    }

    #pragma unroll
    for (int r = 0; r < 4; ++r) {
        red[wid][lane][r]     = acc0[r];
        red[wid][lane][4 + r] = acc1[r];
    }
    __syncthreads();

    // 512 threads: one (lane, slot) each; sum the 8 wave partials.
    const int rlane = tid & 63;
    const int slot  = tid >> 6;          // 0..7 : (token-half h = slot>>2, reg r = slot&3)
    float s = 0.f;
    #pragma unroll
    for (int wv = 0; wv < 8; ++wv) s += red[wv][rlane][slot];

    const int h = slot >> 2;
    const int r = slot & 3;
    const int t = h * 16 + (rlane >> 4) * 4 + r;   // token
    const int o = obase + (rlane & 15);            // output channel

    out[t * OUT_F + o] = s * scale[o] + bias[o];
}

extern "C" void kernel_launch(void* const* d_in, const int* in_sizes, int n_in,
                              void* d_out, int out_size, void* d_ws, size_t ws_size,
                              hipStream_t stream) {
    const float* x     = (const float*)d_in[0];
    const int*   wq    = (const int*)d_in[1];
    const float* scale = (const float*)d_in[2];
    const float* bias  = (const float*)d_in[3];
    float*       out   = (float*)d_out;

    dql_fused<<<OUT_F / 16, 512, 0, stream>>>(x, wq, scale, bias, out);
}